// Round 1
// baseline (30.547 us; speedup 1.0000x reference)
//
#include <hip/hip_runtime.h>
#include <hip/hip_bf16.h>

// Problem constants (match reference)
#define BB 32
#define VV 4
#define JJ 17
#define HH 128
#define WW 128

constexpr int   SLICE   = HH * WW;          // 16384 floats per (b,v,j)
constexpr int   NSLICE  = BB * VV * JJ;     // 2176 slices
constexpr long long NTOT = (long long)NSLICE * SLICE; // 35,651,584

// Kernel 1: one block per (b,v,j) slice. Compute per-slice partial sum of
// (pred - gt)^2 with gt = ey[h]*ex[w] (separable gaussian, sigma=1).
__global__ __launch_bounds__(256)
void heatmap_mse_partial(const float* __restrict__ pred,
                         const float* __restrict__ proj,    // [B,V,3,4]
                         const float* __restrict__ joints,  // [B,J,3]
                         float* __restrict__ partials)      // [NSLICE]
{
    const int bvj = blockIdx.x;
    const int b  = bvj / (VV * JJ);
    const int vj = bvj - b * (VV * JJ);
    const int v  = vj / JJ;
    const int j  = vj - v * JJ;

    // ---- projection (uniform per block; compiler scalarizes these loads) ----
    const float* P = proj + (size_t)(b * VV + v) * 12;
    const float* G = joints + (size_t)(b * JJ + j) * 3;
    const float X = G[0], Y = G[1], Z = G[2];
    const float px = P[0] * X + P[1] * Y + P[2]  * Z + P[3];
    const float py = P[4] * X + P[5] * Y + P[6]  * Z + P[7];
    const float pw = P[8] * X + P[9] * Y + P[10] * Z + P[11];
    const float jx = px / pw;
    const float jy = py / pw;

    // ---- separable gaussian factors in LDS ----
    __shared__ float ex[WW];
    __shared__ float ey[HH];
    const int t = threadIdx.x;
    if (t < WW) {
        float d = (float)t - jx;
        ex[t] = expf(-0.5f * d * d);
    } else {
        int h = t - WW;
        float d = (float)h - jy;
        ey[h] = expf(-0.5f * d * d);
    }
    __syncthreads();

    // ---- stream the slice: 4096 float4, 16 per thread, coalesced ----
    const float4* p4 = (const float4*)(pred + (size_t)bvj * SLICE);
    float acc = 0.0f;
#pragma unroll
    for (int k = 0; k < 16; ++k) {
        const int idx = t + k * 256;     // 0..4095
        const int w4  = idx & 31;        // float4 index within row
        const int h   = idx >> 5;        // row
        const float4 p = p4[idx];
        const float  e = ey[h];
        const float4 x = *(const float4*)(&ex[w4 * 4]);
        float d0 = p.x - e * x.x;
        float d1 = p.y - e * x.y;
        float d2 = p.z - e * x.z;
        float d3 = p.w - e * x.w;
        acc += d0 * d0 + d1 * d1 + d2 * d2 + d3 * d3;
    }

    // ---- block reduction: wave64 shuffle then LDS across 4 waves ----
#pragma unroll
    for (int off = 32; off > 0; off >>= 1)
        acc += __shfl_down(acc, off, 64);
    __shared__ float wsum[4];
    if ((t & 63) == 0) wsum[t >> 6] = acc;
    __syncthreads();
    if (t == 0)
        partials[bvj] = wsum[0] + wsum[1] + wsum[2] + wsum[3];
}

// Kernel 2: deterministic reduction of the 2176 partials -> mean in d_out[0].
__global__ __launch_bounds__(256)
void heatmap_mse_final(const float* __restrict__ partials, float* __restrict__ out)
{
    const int t = threadIdx.x;
    float acc = 0.0f;
    for (int i = t; i < NSLICE; i += 256)
        acc += partials[i];
#pragma unroll
    for (int off = 32; off > 0; off >>= 1)
        acc += __shfl_down(acc, off, 64);
    __shared__ float wsum[4];
    if ((t & 63) == 0) wsum[t >> 6] = acc;
    __syncthreads();
    if (t == 0) {
        float total = wsum[0] + wsum[1] + wsum[2] + wsum[3];
        out[0] = total / (float)NTOT;
    }
}

extern "C" void kernel_launch(void* const* d_in, const int* in_sizes, int n_in,
                              void* d_out, int out_size, void* d_ws, size_t ws_size,
                              hipStream_t stream)
{
    const float* pred   = (const float*)d_in[0];  // [B,V,J,H,W] f32
    const float* proj   = (const float*)d_in[1];  // [B,V,3,4]   f32
    const float* joints = (const float*)d_in[2];  // [B,J,3]     f32
    // d_in[3] = joints_3d_valid_batch (unused by the reference math: all ones)

    float* partials = (float*)d_ws;               // NSLICE floats of scratch
    float* out      = (float*)d_out;

    heatmap_mse_partial<<<NSLICE, 256, 0, stream>>>(pred, proj, joints, partials);
    heatmap_mse_final<<<1, 256, 0, stream>>>(partials, out);
}